// Round 2
// baseline (2496.078 us; speedup 1.0000x reference)
//
#include <hip/hip_runtime.h>

#define B_SZ 2048
#define N_SZ 64
#define H_SZ 256

typedef __bf16 bf16_t;
typedef bf16_t bf16x8 __attribute__((ext_vector_type(8)));
typedef bf16_t bf16x4 __attribute__((ext_vector_type(4)));
typedef float  f32x4  __attribute__((ext_vector_type(4)));

// ---- LDS layout (bf16-element strides) ----
#define SH  264   // lds h:      64 x 256  (+8 pad)
#define SA  136   // lds A:      64 x 128  (+8 pad)
#define SXT 72    // lds X^T:   256 x  64  (+8 pad)
#define SI  520   // lds inputs: 64 x 512  (+8 pad)

#define LH_OFF    0
#define LA_OFF    33792
#define LXT_OFF   51200
#define LIN_OFF   88064
#define LSTAR_OFF 154624   // 256 f32
#define LRED_OFF  155648   // 512 f32
#define LSIM_OFF  157696   // 64 f32
#define LMASK_OFF 157952   // 64 f32
#define LDS_BYTES 158208

// swizzled-weight regions in d_ws (bf16 elements)
#define SWZ_WCAT 0
#define SWZ_WIH  131072
#define SWZ_WHH  (131072 + 393216)

#define LD8(p) (*(const bf16x8*)(p))

__device__ __forceinline__ f32x4 mfma16(bf16x8 a, bf16x8 b, f32x4 c) {
  return __builtin_amdgcn_mfma_f32_16x16x32_bf16(a, b, c, 0, 0, 0);
}
__device__ __forceinline__ float sigm_(float x) { return 1.0f / (1.0f + __expf(-x)); }
__device__ __forceinline__ float tanh_(float x) { return 2.0f / (1.0f + __expf(-2.0f * x)) - 1.0f; }

// Pre-swizzle weights into MFMA B-fragment order (see R1 comment).
__global__ void swz_kernel(const float* __restrict__ W_in, const float* __restrict__ W_out,
                           const float* __restrict__ w_ih, const float* __restrict__ w_hh,
                           bf16_t* __restrict__ ws) {
  const int f = blockIdx.x * blockDim.x + threadIdx.x;
  const float* src;
  bf16_t* dst;
  if (f < 16384) {
    const int fl = f, l = fl & 63, rem = fl >> 6, kb = rem & 7, nt = rem >> 3;
    const int n = nt * 16 + (l & 15), k = kb * 32 + ((l >> 4) << 3);
    src = (n < 256) ? (W_in + n * 256 + k) : (W_out + (n - 256) * 256 + k);
    dst = ws + SWZ_WCAT + (size_t)fl * 8;
  } else if (f < 65536) {
    const int fl = f - 16384, l = fl & 63, rem = fl >> 6, kb = rem & 15, nt = rem >> 4;
    const int n = nt * 16 + (l & 15), k = kb * 32 + ((l >> 4) << 3);
    src = w_ih + n * 512 + k;
    dst = ws + SWZ_WIH + (size_t)fl * 8;
  } else {
    const int fl = f - 65536, l = fl & 63, rem = fl >> 6, kb = rem & 7, nt = rem >> 3;
    const int n = nt * 16 + (l & 15), k = kb * 32 + ((l >> 4) << 3);
    src = w_hh + n * 256 + k;
    dst = ws + SWZ_WHH + (size_t)fl * 8;
  }
  bf16x8 v;
  #pragma unroll
  for (int j = 0; j < 8; ++j) v[j] = (bf16_t)src[j];
  *(bf16x8*)dst = v;
}

__launch_bounds__(512, 2)
__global__ void sgnn_main(
    const float* __restrict__ Aptr, const float* __restrict__ hid,
    const float* __restrict__ gmask,
    const float* __restrict__ b_ih, const float* __restrict__ b_hh,
    const float* __restrict__ b_iah, const float* __restrict__ b_oah,
    const float* __restrict__ b_in, const float* __restrict__ b_out,
    const bf16_t* __restrict__ swzWcat, const bf16_t* __restrict__ swzWih,
    const bf16_t* __restrict__ swzWhh,
    float* __restrict__ out_h, float* __restrict__ out_star) {
  extern __shared__ char lds[];
  bf16_t* lh   = (bf16_t*)(lds + LH_OFF);
  bf16_t* lA   = (bf16_t*)(lds + LA_OFF);
  bf16_t* lXT  = (bf16_t*)(lds + LXT_OFF);
  bf16_t* lin  = (bf16_t*)(lds + LIN_OFF);
  float* lstar = (float*)(lds + LSTAR_OFF);
  float* lred  = (float*)(lds + LRED_OFF);
  float* lsim  = (float*)(lds + LSIM_OFF);
  float* lmask = (float*)(lds + LMASK_OFF);

  const int b = blockIdx.x;
  const int t = threadIdx.x;
  const int w = t >> 6;
  const int l = t & 63;
  const int quad = l >> 4, ln16 = l & 15;

  // ---- preload per-thread biases (reused both steps; same add order as R1) ----
  float pbin[2], pbout[2], pbiah[2], pboah[2], pbr[2], pbz[2], pbi[2], pbh[2];
  #pragma unroll
  for (int nt2 = 0; nt2 < 2; ++nt2) {
    const int c = (2 * w + nt2) * 16 + ln16;
    pbin[nt2] = b_in[c];  pbout[nt2] = b_out[c];
    pbiah[nt2] = b_iah[c]; pboah[nt2] = b_oah[c];
    pbr[nt2] = b_ih[c] + b_hh[c];
    pbz[nt2] = b_ih[256 + c] + b_hh[256 + c];
    pbi[nt2] = b_ih[512 + c];
    pbh[nt2] = b_hh[512 + c];
  }

  // ---- load h (bf16), A (bf16), mask — non-temporal (read exactly once) ----
  {
    const int n = t >> 3, g = t & 7;
    const float* hsrc = hid + ((size_t)b * 64 + n) * 256;
    #pragma unroll
    for (int j = 0; j < 8; ++j) {
      const int c = 4 * (g + 8 * j);
      const f32x4 v = __builtin_nontemporal_load((const f32x4*)(hsrc + c));
      bf16x4 bv = {(bf16_t)v[0], (bf16_t)v[1], (bf16_t)v[2], (bf16_t)v[3]};
      *(bf16x4*)(lh + n * SH + c) = bv;
    }
    const float* asrc = Aptr + ((size_t)b * 64 + n) * 128;
    #pragma unroll
    for (int j = 0; j < 4; ++j) {
      const int c = 4 * (g + 8 * j);
      const f32x4 v = __builtin_nontemporal_load((const f32x4*)(asrc + c));
      bf16x4 bv = {(bf16_t)v[0], (bf16_t)v[1], (bf16_t)v[2], (bf16_t)v[3]};
      *(bf16x4*)(lA + n * SA + c) = bv;
    }
    if (t < 64) lmask[t] = __builtin_nontemporal_load(gmask + (size_t)b * 64 + t);
  }
  __syncthreads();

  // ---- init star ----
  {
    float len = 0.f;
    for (int n2 = 0; n2 < 64; ++n2) len += lmask[n2];
    const int c = t & 255, hf = t >> 8;
    float s = 0.f;
    for (int n2 = hf * 32; n2 < hf * 32 + 32; ++n2)
      s += (float)lh[n2 * SH + c] * lmask[n2];
    lred[t] = s;
    __syncthreads();
    if (t < 256) lstar[t] = (lred[t] + lred[t + 256]) / len;
  }
  __syncthreads();

  for (int step = 0; step < 2; ++step) {
    // ================= Phase 1 =================
    #pragma unroll 1
    for (int half = 0; half < 2; ++half) {
      f32x4 acc[2][4] = {};
      {
        // X = h@Wcat^T : KB=8, depth-3 prefetch, 4-buffer rotation
        const bf16_t* wb = swzWcat + (size_t)(half * 16 + 2 * w) * 4096 + (size_t)l * 8;
        bf16x8 bx[4][2];
        #pragma unroll
        for (int p = 0; p < 3; ++p) {
          bx[p][0] = LD8(wb + p * 512);
          bx[p][1] = LD8(wb + 4096 + p * 512);
        }
        #pragma unroll
        for (int kb = 0; kb < 8; ++kb) {
          if (kb + 3 < 8) {
            bx[(kb + 3) & 3][0] = LD8(wb + (kb + 3) * 512);
            bx[(kb + 3) & 3][1] = LD8(wb + 4096 + (kb + 3) * 512);
          }
          bf16x8 af[4];
          #pragma unroll
          for (int mt = 0; mt < 4; ++mt)
            af[mt] = LD8(lh + (mt * 16 + ln16) * SH + kb * 32 + quad * 8);
          #pragma unroll
          for (int nt2 = 0; nt2 < 2; ++nt2)
            #pragma unroll
            for (int mt = 0; mt < 4; ++mt) acc[nt2][mt] = mfma16(af[mt], bx[kb & 3][nt2], acc[nt2][mt]);
        }
      }
      if (half == 1) __syncthreads();  // protect lXT from half0's readers
      {
        #pragma unroll
        for (int nt2 = 0; nt2 < 2; ++nt2) {
          const int c = (2 * w + nt2) * 16 + ln16;
          const float bb = half ? pbout[nt2] : pbin[nt2];
          #pragma unroll
          for (int mt = 0; mt < 4; ++mt) {
            const int m0 = mt * 16 + quad * 4;
            bf16x4 v = {(bf16_t)(acc[nt2][mt][0] + bb), (bf16_t)(acc[nt2][mt][1] + bb),
                        (bf16_t)(acc[nt2][mt][2] + bb), (bf16_t)(acc[nt2][mt][3] + bb)};
            *(bf16x4*)(lXT + c * SXT + m0) = v;
          }
        }
      }
      __syncthreads();
      // inputs_half = A_half @ X : K=64 (LDS-only operands)
      f32x4 acc2[2][4] = {};
      #pragma unroll
      for (int kb = 0; kb < 2; ++kb) {
        bf16x8 af[4];
        #pragma unroll
        for (int mt = 0; mt < 4; ++mt)
          af[mt] = LD8(lA + (mt * 16 + ln16) * SA + half * 64 + kb * 32 + quad * 8);
        #pragma unroll
        for (int nt2 = 0; nt2 < 2; ++nt2) {
          const int ct = 2 * w + nt2;
          const bf16x8 bfr = LD8(lXT + (ct * 16 + ln16) * SXT + kb * 32 + quad * 8);
          #pragma unroll
          for (int mt = 0; mt < 4; ++mt) acc2[nt2][mt] = mfma16(af[mt], bfr, acc2[nt2][mt]);
        }
      }
      {
        #pragma unroll
        for (int nt2 = 0; nt2 < 2; ++nt2) {
          const int c = (2 * w + nt2) * 16 + ln16;
          const float bb = half ? pboah[nt2] : pbiah[nt2];
          #pragma unroll
          for (int mt = 0; mt < 4; ++mt) {
            const int m0 = mt * 16 + quad * 4;
            #pragma unroll
            for (int i = 0; i < 4; ++i)
              lin[(m0 + i) * SI + half * 256 + c] = (bf16_t)(acc2[nt2][mt][i] + bb);
          }
        }
      }
    }
    __syncthreads();

    // ================= Phase 2a: r,z gates =================
    float rg[2][4][4], zg[2][4][4];
    {
      f32x4 accr[2][4] = {}, accz[2][4] = {};
      {
        const bf16_t* wr = swzWih + (size_t)(2 * w) * 8192 + (size_t)l * 8;
        bf16x8 br[4][2], bz[4][2];
        #pragma unroll
        for (int p = 0; p < 3; ++p)
          #pragma unroll
          for (int nt2 = 0; nt2 < 2; ++nt2) {
            br[p][nt2] = LD8(wr + nt2 * 8192 + p * 512);
            bz[p][nt2] = LD8(wr + 131072 + nt2 * 8192 + p * 512);
          }
        #pragma unroll
        for (int kb = 0; kb < 16; ++kb) {
          if (kb + 3 < 16) {
            #pragma unroll
            for (int nt2 = 0; nt2 < 2; ++nt2) {
              br[(kb + 3) & 3][nt2] = LD8(wr + nt2 * 8192 + (kb + 3) * 512);
              bz[(kb + 3) & 3][nt2] = LD8(wr + 131072 + nt2 * 8192 + (kb + 3) * 512);
            }
          }
          bf16x8 af[4];
          #pragma unroll
          for (int mt = 0; mt < 4; ++mt)
            af[mt] = LD8(lin + (mt * 16 + ln16) * SI + kb * 32 + quad * 8);
          #pragma unroll
          for (int nt2 = 0; nt2 < 2; ++nt2)
            #pragma unroll
            for (int mt = 0; mt < 4; ++mt) {
              accr[nt2][mt] = mfma16(af[mt], br[kb & 3][nt2], accr[nt2][mt]);
              accz[nt2][mt] = mfma16(af[mt], bz[kb & 3][nt2], accz[nt2][mt]);
            }
        }
      }
      {
        const bf16_t* wh = swzWhh + (size_t)(2 * w) * 4096 + (size_t)l * 8;
        bf16x8 br[4][2], bz[4][2];
        #pragma unroll
        for (int p = 0; p < 3; ++p)
          #pragma unroll
          for (int nt2 = 0; nt2 < 2; ++nt2) {
            br[p][nt2] = LD8(wh + nt2 * 4096 + p * 512);
            bz[p][nt2] = LD8(wh + 65536 + nt2 * 4096 + p * 512);
          }
        #pragma unroll
        for (int kb = 0; kb < 8; ++kb) {
          if (kb + 3 < 8) {
            #pragma unroll
            for (int nt2 = 0; nt2 < 2; ++nt2) {
              br[(kb + 3) & 3][nt2] = LD8(wh + nt2 * 4096 + (kb + 3) * 512);
              bz[(kb + 3) & 3][nt2] = LD8(wh + 65536 + nt2 * 4096 + (kb + 3) * 512);
            }
          }
          bf16x8 af[4];
          #pragma unroll
          for (int mt = 0; mt < 4; ++mt)
            af[mt] = LD8(lh + (mt * 16 + ln16) * SH + kb * 32 + quad * 8);
          #pragma unroll
          for (int nt2 = 0; nt2 < 2; ++nt2)
            #pragma unroll
            for (int mt = 0; mt < 4; ++mt) {
              accr[nt2][mt] = mfma16(af[mt], br[kb & 3][nt2], accr[nt2][mt]);
              accz[nt2][mt] = mfma16(af[mt], bz[kb & 3][nt2], accz[nt2][mt]);
            }
        }
      }
      #pragma unroll
      for (int nt2 = 0; nt2 < 2; ++nt2)
        #pragma unroll
        for (int mt = 0; mt < 4; ++mt)
          #pragma unroll
          for (int i = 0; i < 4; ++i) {
            rg[nt2][mt][i] = sigm_(accr[nt2][mt][i] + pbr[nt2]);
            zg[nt2][mt][i] = sigm_(accz[nt2][mt][i] + pbz[nt2]);
          }
    }

    // ================= Phase 2b: n gate + GRU update =================
    {
      f32x4 acci[2][4] = {}, acch[2][4] = {};
      {
        const bf16_t* wn = swzWih + 262144 + (size_t)(2 * w) * 8192 + (size_t)l * 8;
        bf16x8 bn[4][2];
        #pragma unroll
        for (int p = 0; p < 3; ++p)
          #pragma unroll
          for (int nt2 = 0; nt2 < 2; ++nt2) bn[p][nt2] = LD8(wn + nt2 * 8192 + p * 512);
        #pragma unroll
        for (int kb = 0; kb < 16; ++kb) {
          if (kb + 3 < 16) {
            #pragma unroll
            for (int nt2 = 0; nt2 < 2; ++nt2)
              bn[(kb + 3) & 3][nt2] = LD8(wn + nt2 * 8192 + (kb + 3) * 512);
          }
          bf16x8 af[4];
          #pragma unroll
          for (int mt = 0; mt < 4; ++mt)
            af[mt] = LD8(lin + (mt * 16 + ln16) * SI + kb * 32 + quad * 8);
          #pragma unroll
          for (int nt2 = 0; nt2 < 2; ++nt2)
            #pragma unroll
            for (int mt = 0; mt < 4; ++mt) acci[nt2][mt] = mfma16(af[mt], bn[kb & 3][nt2], acci[nt2][mt]);
        }
      }
      {
        const bf16_t* wn = swzWhh + 131072 + (size_t)(2 * w) * 4096 + (size_t)l * 8;
        bf16x8 bn[4][2];
        #pragma unroll
        for (int p = 0; p < 3; ++p)
          #pragma unroll
          for (int nt2 = 0; nt2 < 2; ++nt2) bn[p][nt2] = LD8(wn + nt2 * 4096 + p * 512);
        #pragma unroll
        for (int kb = 0; kb < 8; ++kb) {
          if (kb + 3 < 8) {
            #pragma unroll
            for (int nt2 = 0; nt2 < 2; ++nt2)
              bn[(kb + 3) & 3][nt2] = LD8(wn + nt2 * 4096 + (kb + 3) * 512);
          }
          bf16x8 af[4];
          #pragma unroll
          for (int mt = 0; mt < 4; ++mt)
            af[mt] = LD8(lh + (mt * 16 + ln16) * SH + kb * 32 + quad * 8);
          #pragma unroll
          for (int nt2 = 0; nt2 < 2; ++nt2)
            #pragma unroll
            for (int mt = 0; mt < 4; ++mt) acch[nt2][mt] = mfma16(af[mt], bn[kb & 3][nt2], acch[nt2][mt]);
        }
      }
      __syncthreads();   // all reads of lh done before in-place write
      #pragma unroll
      for (int nt2 = 0; nt2 < 2; ++nt2) {
        const int c = (2 * w + nt2) * 16 + ln16;
        #pragma unroll
        for (int mt = 0; mt < 4; ++mt) {
          const int m0 = mt * 16 + quad * 4;
          #pragma unroll
          for (int i = 0; i < 4; ++i) {
            const float nn = tanh_(acci[nt2][mt][i] + pbi[nt2] + rg[nt2][mt][i] * (acch[nt2][mt][i] + pbh[nt2]));
            const float ho = (float)lh[(m0 + i) * SH + c];
            const float hn = nn + zg[nt2][mt][i] * (ho - nn);
            lh[(m0 + i) * SH + c] = (bf16_t)hn;
          }
        }
      }
    }
    __syncthreads();

    // ================= Phase 3: attention mix + star update =================
    {
      const int n = t >> 3, g = t & 7;
      float hv[32];
      float dot = 0.f;
      #pragma unroll
      for (int j = 0; j < 8; ++j) {
        const int c = 4 * (g + 8 * j);
        const bf16x4 v = *(bf16x4*)(lh + n * SH + c);
        const float4 sv = *(const float4*)(lstar + c);
        hv[4 * j + 0] = (float)v[0]; hv[4 * j + 1] = (float)v[1];
        hv[4 * j + 2] = (float)v[2]; hv[4 * j + 3] = (float)v[3];
        dot += hv[4 * j + 0] * sv.x + hv[4 * j + 1] * sv.y +
               hv[4 * j + 2] * sv.z + hv[4 * j + 3] * sv.w;
      }
      dot += __shfl_xor(dot, 1); dot += __shfl_xor(dot, 2); dot += __shfl_xor(dot, 4);
      const float alpha = sigm_(dot * 0.0625f);
      float dot2 = 0.f;
      #pragma unroll
      for (int j = 0; j < 8; ++j) {
        const int c = 4 * (g + 8 * j);
        const float4 sv = *(const float4*)(lstar + c);
        float m0 = (1.f - alpha) * hv[4 * j + 0] + alpha * sv.x;
        float m1 = (1.f - alpha) * hv[4 * j + 1] + alpha * sv.y;
        float m2 = (1.f - alpha) * hv[4 * j + 2] + alpha * sv.z;
        float m3 = (1.f - alpha) * hv[4 * j + 3] + alpha * sv.w;
        hv[4 * j + 0] = m0; hv[4 * j + 1] = m1; hv[4 * j + 2] = m2; hv[4 * j + 3] = m3;
        dot2 += m0 * sv.x + m1 * sv.y + m2 * sv.z + m3 * sv.w;
      }
      dot2 += __shfl_xor(dot2, 1); dot2 += __shfl_xor(dot2, 2); dot2 += __shfl_xor(dot2, 4);
      #pragma unroll
      for (int j = 0; j < 8; ++j) {
        const int c = 4 * (g + 8 * j);
        bf16x4 bv = {(bf16_t)hv[4 * j + 0], (bf16_t)hv[4 * j + 1],
                     (bf16_t)hv[4 * j + 2], (bf16_t)hv[4 * j + 3]};
        *(bf16x4*)(lh + n * SH + c) = bv;
        if (step == 1) {
          f32x4 ov = {hv[4 * j + 0], hv[4 * j + 1], hv[4 * j + 2], hv[4 * j + 3]};
          __builtin_nontemporal_store(ov, (f32x4*)(out_h + ((size_t)b * 64 + n) * 256 + c));
        }
      }
      const float e = __expf(dot2) * lmask[n];
      if (g == 0) lsim[n] = e;
    }
    __syncthreads();
    {
      float den = 1e-24f;
      for (int n2 = 0; n2 < 64; ++n2) den += lsim[n2];
      const int c = t & 255, hf = t >> 8;
      float s = 0.f;
      for (int n2 = hf * 32; n2 < hf * 32 + 32; ++n2)
        s += lsim[n2] * (float)lh[n2 * SH + c];
      lred[t] = s;
      __syncthreads();
      if (t < 256) {
        const float sn = (lred[t] + lred[t + 256]) / den;
        lstar[t] = sn;
        if (step == 1) __builtin_nontemporal_store(sn, out_star + (size_t)b * 256 + t);
      }
      __syncthreads();
    }
  }
}

extern "C" void kernel_launch(void* const* d_in, const int* in_sizes, int n_in,
                              void* d_out, int out_size, void* d_ws, size_t ws_size,
                              hipStream_t stream) {
  const float* A     = (const float*)d_in[0];
  const float* hid   = (const float*)d_in[1];
  const float* gmask = (const float*)d_in[2];
  const float* w_ih  = (const float*)d_in[3];
  const float* w_hh  = (const float*)d_in[4];
  const float* b_ih  = (const float*)d_in[5];
  const float* b_hh  = (const float*)d_in[6];
  const float* b_iah = (const float*)d_in[7];
  const float* b_oah = (const float*)d_in[8];
  const float* W_in  = (const float*)d_in[9];
  const float* b_in  = (const float*)d_in[10];
  const float* W_out = (const float*)d_in[11];
  const float* b_out = (const float*)d_in[12];
  float* out = (float*)d_out;
  bf16_t* swz = (bf16_t*)d_ws;

  (void)hipFuncSetAttribute((const void*)sgnn_main,
                            hipFuncAttributeMaxDynamicSharedMemorySize, LDS_BYTES);

  swz_kernel<<<352, 256, 0, stream>>>(W_in, W_out, w_ih, w_hh, swz);
  sgnn_main<<<B_SZ, 512, LDS_BYTES, stream>>>(
      A, hid, gmask, b_ih, b_hh, b_iah, b_oah, b_in, b_out,
      swz + SWZ_WCAT, swz + SWZ_WIH, swz + SWZ_WHH,
      out, out + (size_t)B_SZ * N_SZ * H_SZ);
}

// Round 3
// 1234.323 us; speedup vs baseline: 2.0222x; 2.0222x over previous
//
#include <hip/hip_runtime.h>

#define B_SZ 2048
#define N_SZ 64
#define H_SZ 256

typedef __bf16 bf16_t;
typedef bf16_t bf16x8 __attribute__((ext_vector_type(8)));
typedef bf16_t bf16x4 __attribute__((ext_vector_type(4)));
typedef float  f32x4  __attribute__((ext_vector_type(4)));

// ---- workspace layout (bytes) ----
#define OFF_WCAT 0                    // swz Wcat B-frags: 512x256 bf16
#define OFF_WG   262144               // swz gate weights: 768x768 bf16
#define OFF_AB   1441792              // Ab bf16 2048x64x128
#define OFF_HB   34996224             // hb bf16 2048x64x256
#define OFF_HB2  102105088            // hb2 bf16
#define OFF_INP  169213952            // inputs bf16 2048x64x512
#define OFF_STA  303431680            // starA f32 2048x256
#define OFF_STB  305528832            // starB f32

#define NH_EL 33554432   // 2048*64*256
#define NA_EL 16777216   // 2048*64*128

__device__ __forceinline__ f32x4 mfma16(bf16x8 a, bf16x8 b, f32x4 c) {
  return __builtin_amdgcn_mfma_f32_16x16x32_bf16(a, b, c, 0, 0, 0);
}
__device__ __forceinline__ float sigm_(float x) { return 1.0f / (1.0f + __expf(-x)); }
__device__ __forceinline__ float tanh_(float x) { return 2.0f / (1.0f + __expf(-2.0f * x)) - 1.0f; }

typedef const uint32_t __attribute__((address_space(1)))* gas_t;
typedef uint32_t __attribute__((address_space(3)))* las_t;
// async global->LDS, 16 B/lane; LDS dst = wave-uniform base + lane*16
__device__ __forceinline__ void gld_lds(const void* g, void* l) {
  __builtin_amdgcn_global_load_lds((gas_t)g, (las_t)l, 16, 0, 0);
}

// ---------- weight pre-swizzle into MFMA B-fragment order ----------
// B-frag element: n = lane&15, k = (lane>>4)*8 + j
__global__ void swz_kernel(const float* __restrict__ W_in, const float* __restrict__ W_out,
                           const float* __restrict__ w_ih, const float* __restrict__ w_hh,
                           bf16_t* __restrict__ ws) {
  const int f = blockIdx.x * blockDim.x + threadIdx.x;  // frag-lane id (90112 total)
  const float* src;
  bf16_t* dst;
  if (f < 16384) {            // Wcat: (((ng*8+kb)*8+nl)*64+lane)*8
    const int l = f & 63, rem = f >> 6;
    const int nl = rem & 7, rem2 = rem >> 3, kb = rem2 & 7, ng = rem2 >> 3;
    const int c = ng * 128 + nl * 16 + (l & 15);
    const int k = kb * 32 + ((l >> 4) << 3);
    src = (c < 256) ? (W_in + c * 256 + k) : (W_out + (c - 256) * 256 + k);
    dst = ws + (size_t)OFF_WCAT / 2 + (size_t)f * 8;
  } else {                    // Wg: (((ct*24+kb)*6 + g*2+nl)*64+lane)*8
    const int f2 = f - 16384;
    const int l = f2 & 63, rem = f2 >> 6;        // 0..1151
    const int fi = rem % 6, rem2 = rem / 6, kb = rem2 % 24, ct = rem2 / 24;
    const int g = fi >> 1, nl = fi & 1;
    const int rw = g * 256 + ct * 32 + nl * 16 + (l & 15);
    const int kq = (l >> 4) << 3;
    if (kb < 16) src = w_ih + rw * 512 + kb * 32 + kq;
    else         src = w_hh + rw * 256 + (kb - 16) * 32 + kq;
    dst = ws + (size_t)OFF_WG / 2 + (size_t)f2 * 8;
  }
  bf16x8 v;
  #pragma unroll
  for (int j = 0; j < 8; ++j) v[j] = (bf16_t)src[j];
  *(bf16x8*)dst = v;
}

// ---------- f32 -> bf16 conversion of hidden and A ----------
__global__ void convert_kernel(const float* __restrict__ hid, const float* __restrict__ A,
                               bf16_t* __restrict__ hb, bf16_t* __restrict__ ab) {
  const size_t i4 = ((size_t)blockIdx.x * blockDim.x + threadIdx.x) * 4;
  if (i4 < NH_EL) {
    const f32x4 v = *(const f32x4*)(hid + i4);
    bf16x4 o = {(bf16_t)v[0], (bf16_t)v[1], (bf16_t)v[2], (bf16_t)v[3]};
    *(bf16x4*)(hb + i4) = o;
  } else {
    const size_t j4 = i4 - NH_EL;
    const f32x4 v = *(const f32x4*)(A + j4);
    bf16x4 o = {(bf16_t)v[0], (bf16_t)v[1], (bf16_t)v[2], (bf16_t)v[3]};
    *(bf16x4*)(ab + j4) = o;
  }
}

// ---------- star init: star = sum_n hid*mask / sum(mask)  (f32, matches ref) ----------
__global__ void star_init_kernel(const float* __restrict__ hid, const float* __restrict__ gmask,
                                 float* __restrict__ star) {
  const int b = blockIdx.x, c = threadIdx.x;
  float len = 0.f, s = 0.f;
  for (int n = 0; n < 64; ++n) {
    const float m = gmask[(size_t)b * 64 + n];
    len += m;
    s += hid[((size_t)b * 64 + n) * 256 + c] * m;
  }
  star[(size_t)b * 256 + c] = s / len;
}

// ---------- K13: X = h@Wcat^T + b  (in LDS), then inputs = Acat@X + bias ----------
// grid (1024 mtiles, 4 ngroups); 256 thr; m-tile 128 rows = 2 batches
__launch_bounds__(256, 2)
__global__ void k13_kernel(const bf16_t* __restrict__ hb, const bf16_t* __restrict__ ab,
                           const bf16_t* __restrict__ swzWcat,
                           const float* __restrict__ b_in, const float* __restrict__ b_out,
                           const float* __restrict__ b_iah, const float* __restrict__ b_oah,
                           bf16_t* __restrict__ inputs) {
  extern __shared__ char lds[];
  bf16_t* stA = (bf16_t*)lds;                // 8 frags  = 8192 B
  bf16_t* stB = (bf16_t*)(lds + 8192);       // 8 frags  = 8192 B
  bf16_t* CT  = (bf16_t*)(lds + 16384);      // 128 x 136 bf16 = 34816 B (X^T)
  bf16_t* AbF = (bf16_t*)(lds + 51200);      // 16 frags = 16384 B
  const int mtile = blockIdx.x, ng = blockIdx.y;
  const int t = threadIdx.x, w = t >> 6, l = t & 63;
  const int q = l >> 4, l15 = l & 15;
  const int half = ng >> 1, b0 = mtile * 2;

  // stage Ab fragments for GEMM2 up front (async; barriers below cover completion)
  #pragma unroll
  for (int i = 0; i < 4; ++i) {
    const int fidx = w * 4 + i, mt = fidx >> 1, kb2 = fidx & 1;
    const int bloc = b0 + (mt >> 2), m = (mt & 3) * 16 + l15;
    const bf16_t* g = ab + ((size_t)(bloc * 64 + m) * 128 + half * 64 + kb2 * 32 + q * 8);
    gld_lds(g, AbF + fidx * 512);
  }

  // ---- GEMM1: X-tile (128 x 128), K=256 ----
  f32x4 acc[2][8] = {};
  #pragma unroll 1
  for (int kb = 0; kb < 8; ++kb) {
    #pragma unroll
    for (int i = 0; i < 4; ++i) {
      const int f = w * 4 + i;
      if (f < 8) {
        const bf16_t* g = hb + ((size_t)(mtile * 128 + f * 16 + l15) * 256 + kb * 32 + q * 8);
        gld_lds(g, stA + f * 512);
      } else {
        const int fb = f - 8;
        const bf16_t* g = swzWcat + ((size_t)(((ng * 8 + kb) * 8 + fb)) * 64 + l) * 8;
        gld_lds(g, stB + fb * 512);
      }
    }
    __syncthreads();
    const bf16x8 a0 = *(const bf16x8*)(stA + (2 * w) * 512 + l * 8);
    const bf16x8 a1 = *(const bf16x8*)(stA + (2 * w + 1) * 512 + l * 8);
    #pragma unroll
    for (int nt = 0; nt < 8; ++nt) {
      const bf16x8 bf = *(const bf16x8*)(stB + nt * 512 + l * 8);
      acc[0][nt] = mfma16(a0, bf, acc[0][nt]);
      acc[1][nt] = mfma16(a1, bf, acc[1][nt]);
    }
    __syncthreads();
  }
  // epilogue: bias + bf16, store X^T into CT
  #pragma unroll
  for (int nt = 0; nt < 8; ++nt) {
    const int cl = nt * 16 + l15, cg = ng * 128 + cl;
    const float bb = (cg < 256) ? b_in[cg] : b_out[cg - 256];
    #pragma unroll
    for (int mti = 0; mti < 2; ++mti) {
      const int kloc = w * 32 + mti * 16 + q * 4;
      bf16x4 v = {(bf16_t)(acc[mti][nt][0] + bb), (bf16_t)(acc[mti][nt][1] + bb),
                  (bf16_t)(acc[mti][nt][2] + bb), (bf16_t)(acc[mti][nt][3] + bb)};
      *(bf16x4*)(CT + cl * 136 + kloc) = v;
    }
  }
  __syncthreads();

  // ---- GEMM2: inputs-tile = Acat @ X (K=64, per-batch block) ----
  f32x4 acc2[2][8] = {};
  const int bblk = (w >> 1) * 64;
  #pragma unroll
  for (int kb2 = 0; kb2 < 2; ++kb2) {
    const bf16x8 a0 = *(const bf16x8*)(AbF + ((2 * w) * 2 + kb2) * 512 + l * 8);
    const bf16x8 a1 = *(const bf16x8*)(AbF + ((2 * w + 1) * 2 + kb2) * 512 + l * 8);
    #pragma unroll
    for (int nt = 0; nt < 8; ++nt) {
      const bf16x8 bf = *(const bf16x8*)(CT + (nt * 16 + l15) * 136 + bblk + kb2 * 32 + q * 8);
      acc2[0][nt] = mfma16(a0, bf, acc2[0][nt]);
      acc2[1][nt] = mfma16(a1, bf, acc2[1][nt]);
    }
  }
  const int bglob = b0 + (w >> 1);
  #pragma unroll
  for (int nt = 0; nt < 8; ++nt) {
    const int c512 = ng * 128 + nt * 16 + l15;
    const float bb = (c512 < 256) ? b_iah[c512] : b_oah[c512 - 256];
    #pragma unroll
    for (int mti = 0; mti < 2; ++mti)
      #pragma unroll
      for (int i = 0; i < 4; ++i) {
        const int mloc = (w & 1) * 32 + mti * 16 + q * 4 + i;
        inputs[((size_t)(bglob * 64 + mloc)) * 512 + c512] = (bf16_t)(acc2[mti][nt][i] + bb);
      }
  }
}

// ---------- K3: gates GEMM (K=512 inputs + 256 h) + GRU update ----------
// grid (1024 mtiles, 8 ctiles of 32); 256 thr
__launch_bounds__(256, 2)
__global__ void k3_kernel(const bf16_t* __restrict__ inputs, const bf16_t* __restrict__ hb,
                          const bf16_t* __restrict__ swzWg,
                          const float* __restrict__ b_ih, const float* __restrict__ b_hh,
                          bf16_t* __restrict__ hb2) {
  extern __shared__ char lds[];
  bf16_t* stA = (bf16_t*)lds;            // 8 frags = 8192 B
  bf16_t* stB = (bf16_t*)(lds + 8192);   // 6 frags = 6144 B
  const int mtile = blockIdx.x, ct = blockIdx.y;
  const int t = threadIdx.x, w = t >> 6, l = t & 63;
  const int q = l >> 4, l15 = l & 15;

  f32x4 accR[2][2] = {}, accZ[2][2] = {}, accNI[2][2] = {}, accNH[2][2] = {};
  #pragma unroll 1
  for (int kb = 0; kb < 24; ++kb) {
    if (w < 2) {
      #pragma unroll
      for (int i = 0; i < 4; ++i) {
        const int f = w * 4 + i;
        const int row = mtile * 128 + f * 16 + l15;
        const bf16_t* g = (kb < 16)
          ? inputs + ((size_t)row * 512 + kb * 32 + q * 8)
          : hb + ((size_t)row * 256 + (kb - 16) * 32 + q * 8);
        gld_lds(g, stA + f * 512);
      }
    } else {
      #pragma unroll
      for (int i = 0; i < 3; ++i) {
        const int fb = (w - 2) * 3 + i;
        const bf16_t* g = swzWg + ((size_t)((ct * 24 + kb) * 6 + fb) * 64 + l) * 8;
        gld_lds(g, stB + fb * 512);
      }
    }
    __syncthreads();
    bf16x8 a[2];
    a[0] = *(const bf16x8*)(stA + (2 * w) * 512 + l * 8);
    a[1] = *(const bf16x8*)(stA + (2 * w + 1) * 512 + l * 8);
    #pragma unroll
    for (int g3 = 0; g3 < 3; ++g3)
      #pragma unroll
      for (int nl = 0; nl < 2; ++nl) {
        const bf16x8 bf = *(const bf16x8*)(stB + (g3 * 2 + nl) * 512 + l * 8);
        #pragma unroll
        for (int mti = 0; mti < 2; ++mti) {
          if (g3 == 0)      accR[mti][nl] = mfma16(a[mti], bf, accR[mti][nl]);
          else if (g3 == 1) accZ[mti][nl] = mfma16(a[mti], bf, accZ[mti][nl]);
          else if (kb < 16) accNI[mti][nl] = mfma16(a[mti], bf, accNI[mti][nl]);
          else              accNH[mti][nl] = mfma16(a[mti], bf, accNH[mti][nl]);
        }
      }
    __syncthreads();
  }
  // epilogue: gates + GRU
  #pragma unroll
  for (int nl = 0; nl < 2; ++nl) {
    const int c = ct * 32 + nl * 16 + l15;
    const float brv = b_ih[c] + b_hh[c];
    const float bzv = b_ih[256 + c] + b_hh[256 + c];
    const float biv = b_ih[512 + c];
    const float bhv = b_hh[512 + c];
    #pragma unroll
    for (int mti = 0; mti < 2; ++mti)
      #pragma unroll
      for (int i = 0; i < 4; ++i) {
        const size_t m = (size_t)mtile * 128 + w * 32 + mti * 16 + q * 4 + i;
        const float r = sigm_(accR[mti][nl][i] + brv);
        const float z = sigm_(accZ[mti][nl][i] + bzv);
        const float nn = tanh_(accNI[mti][nl][i] + biv + r * (accNH[mti][nl][i] + bhv));
        const float ho = (float)hb[m * 256 + c];
        hb2[m * 256 + c] = (bf16_t)(nn + z * (ho - nn));
      }
  }
}

// ---------- K4: attention mix + star update (per batch) ----------
__launch_bounds__(256, 2)
__global__ void k4_kernel(const bf16_t* __restrict__ hsrc, const float* __restrict__ star_in,
                          const float* __restrict__ gmask,
                          bf16_t* __restrict__ hb_out, float* __restrict__ star_out,
                          float* __restrict__ out_h, float* __restrict__ out_star,
                          const int is_last) {
  __shared__ bf16_t lhm[64 * 264];
  __shared__ float le[64];
  const int b = blockIdx.x, t = threadIdx.x;
  const int n = t >> 2, qq = t & 3, cbase = qq * 64;

  float hv[64], sv[64];
  float dot = 0.f;
  #pragma unroll
  for (int j = 0; j < 8; ++j) {
    const bf16x8 v = *(const bf16x8*)(hsrc + ((size_t)b * 64 + n) * 256 + cbase + j * 8);
    #pragma unroll
    for (int i = 0; i < 8; ++i) hv[j * 8 + i] = (float)v[i];
  }
  #pragma unroll
  for (int j = 0; j < 16; ++j) {
    const f32x4 s4 = *(const f32x4*)(star_in + (size_t)b * 256 + cbase + j * 4);
    sv[j * 4 + 0] = s4[0]; sv[j * 4 + 1] = s4[1]; sv[j * 4 + 2] = s4[2]; sv[j * 4 + 3] = s4[3];
  }
  #pragma unroll
  for (int i = 0; i < 64; ++i) dot += hv[i] * sv[i];
  dot += __shfl_xor(dot, 1); dot += __shfl_xor(dot, 2);
  const float alpha = sigm_(dot * 0.0625f);
  float dot2 = 0.f;
  #pragma unroll
  for (int i = 0; i < 64; ++i) {
    hv[i] = (1.f - alpha) * hv[i] + alpha * sv[i];
    dot2 += hv[i] * sv[i];
  }
  dot2 += __shfl_xor(dot2, 1); dot2 += __shfl_xor(dot2, 2);
  const float e = __expf(dot2) * gmask[(size_t)b * 64 + n];
  if (qq == 0) le[n] = e;
  // store mixed h (bf16 into LDS for star; global out per step)
  #pragma unroll
  for (int j = 0; j < 8; ++j) {
    bf16x8 v;
    #pragma unroll
    for (int i = 0; i < 8; ++i) v[i] = (bf16_t)hv[j * 8 + i];
    *(bf16x8*)(lhm + n * 264 + cbase + j * 8) = v;
    if (is_last) {
      f32x4 o = {hv[j * 8 + 0], hv[j * 8 + 1], hv[j * 8 + 2], hv[j * 8 + 3]};
      f32x4 o2 = {hv[j * 8 + 4], hv[j * 8 + 5], hv[j * 8 + 6], hv[j * 8 + 7]};
      *(f32x4*)(out_h + ((size_t)b * 64 + n) * 256 + cbase + j * 8) = o;
      *(f32x4*)(out_h + ((size_t)b * 64 + n) * 256 + cbase + j * 8 + 4) = o2;
    } else {
      *(bf16x8*)(hb_out + ((size_t)b * 64 + n) * 256 + cbase + j * 8) = v;
    }
  }
  __syncthreads();
  float den = 1e-24f;
  for (int n2 = 0; n2 < 64; ++n2) den += le[n2];
  const int c = t;  // 0..255
  float s = 0.f;
  for (int n2 = 0; n2 < 64; ++n2) s += le[n2] * (float)lhm[n2 * 264 + c];
  const float sn = s / den;
  if (is_last) out_star[(size_t)b * 256 + c] = sn;
  else         star_out[(size_t)b * 256 + c] = sn;
}

extern "C" void kernel_launch(void* const* d_in, const int* in_sizes, int n_in,
                              void* d_out, int out_size, void* d_ws, size_t ws_size,
                              hipStream_t stream) {
  const float* A     = (const float*)d_in[0];
  const float* hid   = (const float*)d_in[1];
  const float* gmask = (const float*)d_in[2];
  const float* w_ih  = (const float*)d_in[3];
  const float* w_hh  = (const float*)d_in[4];
  const float* b_ih  = (const float*)d_in[5];
  const float* b_hh  = (const float*)d_in[6];
  const float* b_iah = (const float*)d_in[7];
  const float* b_oah = (const float*)d_in[8];
  const float* W_in  = (const float*)d_in[9];
  const float* b_in  = (const float*)d_in[10];
  const float* W_out = (const float*)d_in[11];
  const float* b_out = (const float*)d_in[12];
  float* out = (float*)d_out;
  char* ws = (char*)d_ws;

  bf16_t* swzWcat = (bf16_t*)(ws + OFF_WCAT);
  bf16_t* swzWg   = (bf16_t*)(ws + OFF_WG);
  bf16_t* ab      = (bf16_t*)(ws + OFF_AB);
  bf16_t* hb      = (bf16_t*)(ws + OFF_HB);
  bf16_t* hb2     = (bf16_t*)(ws + OFF_HB2);
  bf16_t* inputs  = (bf16_t*)(ws + OFF_INP);
  float*  starA   = (float*)(ws + OFF_STA);
  float*  starB   = (float*)(ws + OFF_STB);
  float* out_h    = out;
  float* out_star = out + (size_t)B_SZ * N_SZ * H_SZ;

  (void)hipFuncSetAttribute((const void*)k13_kernel,
                            hipFuncAttributeMaxDynamicSharedMemorySize, 67584);

  swz_kernel<<<352, 256, 0, stream>>>(W_in, W_out, w_ih, w_hh, (bf16_t*)ws);
  convert_kernel<<<49152, 256, 0, stream>>>(hid, A, hb, ab);
  star_init_kernel<<<2048, 256, 0, stream>>>(hid, gmask, starA);

  // step 0
  k13_kernel<<<dim3(1024, 4), 256, 67584, stream>>>(hb, ab, swzWcat, b_in, b_out, b_iah, b_oah, inputs);
  k3_kernel<<<dim3(1024, 8), 256, 14336, stream>>>(inputs, hb, swzWg, b_ih, b_hh, hb2);
  k4_kernel<<<2048, 256, 0, stream>>>(hb2, starA, gmask, hb, starB, out_h, out_star, 0);
  // step 1
  k13_kernel<<<dim3(1024, 4), 256, 67584, stream>>>(hb, ab, swzWcat, b_in, b_out, b_iah, b_oah, inputs);
  k3_kernel<<<dim3(1024, 8), 256, 14336, stream>>>(inputs, hb, swzWg, b_ih, b_hh, hb2);
  k4_kernel<<<2048, 256, 0, stream>>>(hb2, starB, gmask, hb, starA, out_h, out_star, 1);
}